// Round 7
// baseline (4242.845 us; speedup 1.0000x reference)
//
#include <hip/hip_runtime.h>
#include <cstdint>
#include <cstddef>

// ---------------------------------------------------------------------------
// LSTM  B=64, T=1024, D=H=512.
//   * xcvt: x_seq fp32 -> fp16 in ws (one-time).
//   * lstm_rec: persistent, 256 WGs = 8 batch-groups x 32 column-groups.
//     WG (g,c): batch rows g*8..g*8+7, hidden units c*16..c*16+15.
//     Wh & Wx slices LDS-resident fp16 (1 WG/CU).
//     Tagged h (tag<<16|fp16) double-buffered; whole-WG cooperative
//     spin-load IS the data load (verified 4018.8us structure, R9 anchor
//     reproduced EXACTLY -> env stable, baseline counters trusted).
//   R10: TRANSPOSED-GATE ELEMENTWISE (one structural change).
//     Old: wave=gate-segment => gates of unit u spread across 4 waves =>
//     gs-LDS write + barrier2 + wave-0-only serial elementwise (192 lanes
//     idle, 2 units/thread serial transcendental chains).
//     New: swap MFMA operands (A=W-frag, B=h/x-frag; both frags use
//     lane&15 + quad*8 so per-lane data is IDENTICAL — proven by the
//     working kernel) => D transposed: row=gate-row, col=batch. Weight
//     LDS rows interleaved (row r = gate r&3 of unit r>>2) so each lane's
//     4 acc regs = {f,i,g,o} of ONE (unit=w*4+quad, batch=l15&7) pair.
//       * elementwise fully lane-parallel, no gs, no barrier 2
//       * publish per-wave ASAP (u32 tagged store, lanes l15<8)
//       * hls double-buffered (+8.3KB LDS, 149.8KB total, still 1 WG/CU)
//         so dropping barrier 2 cannot race hls re-staging.
//     Untouched (fragile equilibrium): spin loop, agent-scope transport,
//     __syncthreads after stage, bottom-of-loop x-GEMM backoff placement.
// ---------------------------------------------------------------------------

typedef _Float16 half8  __attribute__((ext_vector_type(8)));
typedef _Float16 half4v __attribute__((ext_vector_type(4)));
typedef float    float4v __attribute__((ext_vector_type(4)));

__device__ __forceinline__ float sigm(float x) { return 1.f / (1.f + __expf(-x)); }
__device__ __forceinline__ float tanh_f(float x) { return 2.f / (1.f + __expf(-2.f * x)) - 1.f; }

// ----------------------------- x fp32 -> fp16 ------------------------------
__global__ __launch_bounds__(256) void xcvt(const float* __restrict__ X,
                                            _Float16* __restrict__ XH) {
    size_t i = ((size_t)blockIdx.x * 256 + threadIdx.x) * 8;
    float4 a = *(const float4*)(X + i);
    float4 b = *(const float4*)(X + i + 4);
    half8 v;
    v[0] = (_Float16)a.x; v[1] = (_Float16)a.y; v[2] = (_Float16)a.z; v[3] = (_Float16)a.w;
    v[4] = (_Float16)b.x; v[5] = (_Float16)b.y; v[6] = (_Float16)b.z; v[7] = (_Float16)b.w;
    *(half8*)(XH + i) = v;
}

// ------------------------------- recurrence --------------------------------
__global__ __launch_bounds__(256, 1) void lstm_rec(
    const float* __restrict__ Whf, const float* __restrict__ Whi,
    const float* __restrict__ Whg, const float* __restrict__ Who,
    const float* __restrict__ Wxf, const float* __restrict__ Wxi,
    const float* __restrict__ Wxg, const float* __restrict__ Wxo,
    const float* __restrict__ bxf, const float* __restrict__ bxi,
    const float* __restrict__ bxg, const float* __restrict__ bxo,
    const float* __restrict__ bhf, const float* __restrict__ bhi,
    const float* __restrict__ bhg, const float* __restrict__ bho,
    const _Float16* __restrict__ XH,        // [64][1024][512] fp16
    unsigned long long* __restrict__ hws,   // tagged h [2][8][8][256] u64, zeroed
    float* __restrict__ out)                // [64][512] fp32
{
    const int blk  = blockIdx.x;
    const int g    = blk & 7;    // batch group
    const int c    = blk >> 3;   // column group 0..31
    const int tid  = threadIdx.x;
    const int w    = tid >> 6;   // wave 0..3 -> units w*4..w*4+3 (local)
    const int lane = tid & 63;
    const int l15  = lane & 15;
    const int quad = lane >> 4;
    const int m    = l15 & 7;    // batch row (cols 8..15 dup 0..7)

    __shared__ _Float16 Wls[64][520];     // Wh slice, row r = gate r&3, unit r>>2
    __shared__ _Float16 Xls[64][520];     // Wx slice, same interleave
    __shared__ _Float16 hls[2][8][520];   // staged h_t payload, double-buffered

    // ---- one-time: weight slices -> LDS fp16 (interleaved rows) ----
    const float* WhSeg[4] = {Whf, Whi, Whg, Who};
    const float* WxSeg[4] = {Wxf, Wxi, Wxg, Wxo};
    for (int e = tid * 4; e < 64 * 512; e += 1024) {
        int row = e >> 9, col = e & 511;
        int gate = row & 3;                 // f,i,g,o
        int srow = c * 16 + (row >> 2);     // global unit
        float4 vh = *(const float4*)(WhSeg[gate] + (size_t)srow * 512 + col);
        float4 vx = *(const float4*)(WxSeg[gate] + (size_t)srow * 512 + col);
        half4v th = {(_Float16)vh.x, (_Float16)vh.y, (_Float16)vh.z, (_Float16)vh.w};
        half4v tx = {(_Float16)vx.x, (_Float16)vx.y, (_Float16)vx.z, (_Float16)vx.w};
        *(half4v*)&Wls[row][col] = th;
        *(half4v*)&Xls[row][col] = tx;
    }
    __syncthreads();

    // ---- per-lane roles: this lane owns (unit ul, batch m) ----
    const int ul = w * 4 + quad;          // local unit 0..15
    const int ug = c * 16 + ul;           // global unit
    float bsf = bxf[ug] + bhf[ug];
    float bsi = bxi[ug] + bhi[ug];
    float bsg = bxg[ug] + bhg[ug];
    float bso = bxo[ug] + bho[ug];
    float cst = 0.f;

    // consumer staging role: lane loads 8 u64 (16 tagged u32) of group h
    const int crow = tid >> 5;          // 0..7
    const int ccol = (tid & 31) << 4;   // 0..496

    // ---- x-projection shadow: acc_x for step 0 (A=Wx-frag, B=x-frag) ----
    const size_t xrow = (size_t)(g * 8 + m) * 1024 * 512 + (size_t)quad * 8;
    half8 xf[16];
#pragma unroll
    for (int kk = 0; kk < 16; kk++) xf[kk] = *(const half8*)(XH + xrow + kk * 32);
    float4v accx = {0.f, 0.f, 0.f, 0.f};
#pragma unroll
    for (int kk = 0; kk < 16; kk++) {
        half8 a = *(const half8*)&Xls[w * 16 + l15][kk * 32 + quad * 8];
        accx = __builtin_amdgcn_mfma_f32_16x16x32_f16(a, xf[kk], accx, 0, 0, 0);
    }

    for (int t = 0; t < 1024; t++) {
        // ---- cooperative tagged spin-load of h_t -> LDS (poll IS the load)
        {
            const unsigned long long* hsrc = hws + (size_t)(t & 1) * 16384
                                           + (size_t)g * 2048 + (size_t)tid * 8;
            const unsigned long long T =
                ((unsigned long long)(unsigned)t << 16) |
                ((unsigned long long)(unsigned)t << 48);
            unsigned long long q[8];
            for (;;) {
                unsigned long long bad = 0;
#pragma unroll
                for (int j = 0; j < 8; j++)
                    q[j] = __hip_atomic_load(hsrc + j, __ATOMIC_RELAXED,
                                             __HIP_MEMORY_SCOPE_AGENT);
#pragma unroll
                for (int j = 0; j < 8; j++)
                    bad |= (q[j] ^ T) & 0xFFFF0000FFFF0000ULL;
                if (!bad) break;
            }
            unsigned int* hd = (unsigned int*)&hls[t & 1][crow][ccol];
#pragma unroll
            for (int j = 0; j < 8; j++)
                hd[j] = (unsigned int)(q[j] & 0xFFFF) |
                        (((unsigned int)(q[j] >> 32)) << 16);
        }
        __syncthreads();

        // ---- h-GEMM: acc = acc_x + Wh_slice @ h_t  (A=W rows, B=h cols) ----
        float4v acca = accx;
        float4v accb = {0.f, 0.f, 0.f, 0.f};
#pragma unroll
        for (int kk = 0; kk < 16; kk += 2) {
            half8 b0 = *(const half8*)&hls[t & 1][m][kk * 32 + quad * 8];
            half8 b1 = *(const half8*)&hls[t & 1][m][(kk + 1) * 32 + quad * 8];
            half8 a0 = *(const half8*)&Wls[w * 16 + l15][kk * 32 + quad * 8];
            half8 a1 = *(const half8*)&Wls[w * 16 + l15][(kk + 1) * 32 + quad * 8];
            acca = __builtin_amdgcn_mfma_f32_16x16x32_f16(a0, b0, acca, 0, 0, 0);
            accb = __builtin_amdgcn_mfma_f32_16x16x32_f16(a1, b1, accb, 0, 0, 0);
        }

        // ---- per-lane elementwise: 4 acc regs = {f,i,g,o} of (ul, m) ----
        {
            float pf = acca[0] + accb[0] + bsf;
            float pi = acca[1] + accb[1] + bsi;
            float pg = acca[2] + accb[2] + bsg;
            float po = acca[3] + accb[3] + bso;
            cst = sigm(pf) * cst + sigm(pi) * tanh_f(pg);
            float hn = sigm(po) * tanh_f(cst);
            if (l15 < 8) {
                union { _Float16 f; unsigned short u; } cv;
                cv.f = (_Float16)hn;
                unsigned qv = ((unsigned)(t + 1) << 16) | cv.u;
                unsigned* hd32 = (unsigned*)hws;
                __hip_atomic_store(&hd32[(size_t)((t + 1) & 1) * 32768
                                         + (size_t)g * 4096 + (size_t)m * 512 + ug],
                                   qv, __ATOMIC_RELAXED, __HIP_MEMORY_SCOPE_AGENT);
                if (t == 1023) {
                    out[(size_t)(g * 8 + m) * 512 + ug] = hn;
                }
            }
        }

        // ---- shadow x-GEMM for step t+1 (off critical path, backoff) ----
        int tn = (t < 1023) ? (t + 1) : 0;
        const _Float16* xp = XH + xrow + (size_t)tn * 512;
#pragma unroll
        for (int kk = 0; kk < 16; kk++) xf[kk] = *(const half8*)(xp + kk * 32);
        float4v ax = {0.f, 0.f, 0.f, 0.f};
#pragma unroll
        for (int kk = 0; kk < 16; kk++) {
            half8 a = *(const half8*)&Xls[w * 16 + l15][kk * 32 + quad * 8];
            ax = __builtin_amdgcn_mfma_f32_16x16x32_f16(a, xf[kk], ax, 0, 0, 0);
        }
        accx = ax;
    }
}

// ------------------------------- launcher ----------------------------------
extern "C" void kernel_launch(void* const* d_in, const int* in_sizes, int n_in,
                              void* d_out, int out_size, void* d_ws, size_t ws_size,
                              hipStream_t stream) {
    const float* X   = (const float*)d_in[0];
    const float* Whf = (const float*)d_in[1];  const float* bhf = (const float*)d_in[2];
    const float* Wxf = (const float*)d_in[3];  const float* bxf = (const float*)d_in[4];
    const float* Whi = (const float*)d_in[5];  const float* bhi = (const float*)d_in[6];
    const float* Wxi = (const float*)d_in[7];  const float* bxi = (const float*)d_in[8];
    const float* Whg = (const float*)d_in[9];  const float* bhg = (const float*)d_in[10];
    const float* Wxg = (const float*)d_in[11]; const float* bxg = (const float*)d_in[12];
    const float* Who = (const float*)d_in[13]; const float* bho = (const float*)d_in[14];
    const float* Wxo = (const float*)d_in[15]; const float* bxo = (const float*)d_in[16];

    // ws layout: [0,256KB) tagged h double buffer | [1MB,65MB) XH fp16
    if (ws_size < (size_t)68157440) return;  // need 65 MiB

    char* ws = (char*)d_ws;
    unsigned long long* hws = (unsigned long long*)ws;
    _Float16*           XH  = (_Float16*)(ws + (1 << 20));
    (void)in_sizes; (void)n_in; (void)out_size;

    hipMemsetAsync(d_ws, 0, 262144, stream);
    xcvt<<<16384, 256, 0, stream>>>(X, XH);
    lstm_rec<<<256, 256, 0, stream>>>(Whf, Whi, Whg, Who, Wxf, Wxi, Wxg, Wxo,
                                      bxf, bxi, bxg, bxo, bhf, bhi, bhg, bho,
                                      XH, hws, (float*)d_out);
}